// Round 6
// baseline (207.645 us; speedup 1.0000x reference)
//
#include <hip/hip_runtime.h>
#include <math.h>

#define L_TOK 16
#define DMODEL 1024
#define NHEAD 16
#define DHEAD 64
#define NBLK 1024
#define BSZ 16
#define START_POS_C 16368
#define TTOT 16384
#define SPLITS 128
#define CHUNK 128          // tokens per block (4 waves x 32 tokens)
#define KSPLIT 16
#define QSCALE (0.125f * 1.4426950408889634f)   // 1/sqrt(64) * log2(e)

// workspace offsets, in floats
#define OFF_QKVP 0                                          // 16*16*3072 = 786432
#define OFF_QW   (OFF_QKVP + KSPLIT * L_TOK * 3 * DMODEL)   // 786432
#define OFF_ACC  (OFF_QW + NHEAD * L_TOK * DHEAD)           // 802816
#define OFF_M    (OFF_ACC + NHEAD * SPLITS * L_TOK * DHEAD) // 2899968
#define OFF_SE   (OFF_M + NHEAD * SPLITS * L_TOK)           // 2932736
#define OFF_ATTN (OFF_SE + NHEAD * SPLITS * L_TOK)          // 2965504
#define OFF_PROJP (OFF_ATTN + L_TOK * DMODEL)               // 2981888
// end = 3244032 floats = 12.4 MB

typedef _Float16 half4_t __attribute__((ext_vector_type(4)));
typedef _Float16 half8_t __attribute__((ext_vector_type(8)));
typedef float float4v __attribute__((ext_vector_type(4)));

union H8 { _Float16 h[8]; half8_t v; };
union H4 { _Float16 h[4]; half4_t v; };

// ---------------------------------------------------------------------------
// Split-K partial GEMM, vectorized (unchanged from r5).
// ---------------------------------------------------------------------------
__global__ __launch_bounds__(256) void gemm_part(const float* __restrict__ x,
                                                 const float* __restrict__ W,
                                                 float* __restrict__ part,
                                                 int ncols) {
    const int lane = threadIdx.x & 63;
    const int wv = threadIdx.x >> 6;
    const int n = blockIdx.x * 256 + lane * 4;
    const int k0 = blockIdx.y * (DMODEL / KSPLIT);
    const float* xr = x + (size_t)(wv * 4) * DMODEL;
    float4v a0 = {0.f,0.f,0.f,0.f}, a1 = a0, a2 = a0, a3 = a0;
#pragma unroll 4
    for (int k = k0; k < k0 + DMODEL / KSPLIT; ++k) {
        float4v w4 = *(const float4v*)&W[(size_t)k * ncols + n];
        float x0 = xr[k];
        float x1 = xr[DMODEL + k];
        float x2 = xr[2 * DMODEL + k];
        float x3 = xr[3 * DMODEL + k];
        a0 += w4 * x0;
        a1 += w4 * x1;
        a2 += w4 * x2;
        a3 += w4 * x3;
    }
    size_t base = ((size_t)blockIdx.y * L_TOK + wv * 4) * ncols + n;
    *(float4v*)&part[base] = a0;
    *(float4v*)&part[base + (size_t)ncols] = a1;
    *(float4v*)&part[base + 2 * (size_t)ncols] = a2;
    *(float4v*)&part[base + 3 * (size_t)ncols] = a3;
}

// ---------------------------------------------------------------------------
// Reduce split-K partials of QKV, add bias, scatter (unchanged).
// ---------------------------------------------------------------------------
__global__ __launch_bounds__(256) void qkv_reduce_scatter(const float* __restrict__ part,
                                                          const float* __restrict__ b_attn,
                                                          const int* __restrict__ block_ids,
                                                          float* __restrict__ qws,
                                                          float* __restrict__ kpool,
                                                          float* __restrict__ vpool) {
    int tid = blockIdx.x * 256 + threadIdx.x;
    int n = tid % (3 * DMODEL);
    int l = tid / (3 * DMODEL);
    float s = b_attn[n];
#pragma unroll
    for (int kb = 0; kb < KSPLIT; ++kb)
        s += part[((size_t)kb * L_TOK + l) * (3 * DMODEL) + n];
    int sec = n >> 10;
    int m = n & (DMODEL - 1);
    int h = m >> 6;
    int dd = m & 63;
    if (sec == 0) {
        qws[(h * L_TOK + l) * DHEAD + dd] = s * QSCALE;
    } else {
        int pos = START_POS_C + l;
        int blk = block_ids[pos >> 4];
        int off = pos & 15;
        size_t idx = (((size_t)blk * BSZ + off) * NHEAD + h) * DHEAD + dd;
        if (sec == 1) kpool[idx] = s;
        else          vpool[idx] = s;
    }
}

// ---------------------------------------------------------------------------
// Flash-decode paged attention v6 = v5 + PINNED load-first schedule.
// grid = (NHEAD, SPLITS), block = 256 (4 waves x 32 tokens, single-shot
// softmax). All 52 VMEM loads are issued before sched_barrier(0); the
// barrier forbids the scheduler from sinking them to uses, so the results
// (~130 VGPRs) stay in flight. __launch_bounds__(256,3) raises the VGPR
// cap to ~168 so regalloc doesn't spill. Use order == load order
// (q -> K -> V) so waitcnts drain progressively, not vmcnt(0) up front.
// ---------------------------------------------------------------------------
__global__ __launch_bounds__(256, 3) void paged_attn(const float* __restrict__ kpool,
                                                     const float* __restrict__ vpool,
                                                     const int* __restrict__ block_ids,
                                                     const float* __restrict__ qws,
                                                     float* __restrict__ accws,
                                                     float* __restrict__ m_arr,
                                                     float* __restrict__ se_arr) {
    const int h = blockIdx.x;
    const int s = blockIdx.y;
    const int tid = threadIdx.x;
    const int w = tid >> 6;
    const int lane = tid & 63;
    const int c = lane & 15;
    const int quad = lane >> 4;

    __shared__ __align__(16) float sacc[4][16][68];   // stride 68: 2-way banks
    __shared__ float sm[4][16], sse[4][16];

    const int pb0 = block_ids[s * 8 + 2 * w];
    const int pb1 = block_ids[s * 8 + 2 * w + 1];
    const int tb0 = s * CHUNK + w * 32;
    const int tb1 = tb0 + 16;

    // ==================== LOAD BLOCK (issue everything) ====================
    // q first (warm, tiny), then K, then V — matches consumption order.
    const float* qr = qws + ((size_t)(h * L_TOK + c)) * DHEAD + quad * 8;
    float4 q0 = *(const float4*)(qr);
    float4 q1 = *(const float4*)(qr + 4);
    float4 q2 = *(const float4*)(qr + 32);
    float4 q3 = *(const float4*)(qr + 36);

    const float* kr0 = kpool + (((size_t)pb0 * BSZ + c) * NHEAD + h) * DHEAD + quad * 8;
    const float* kr1 = kpool + (((size_t)pb1 * BSZ + c) * NHEAD + h) * DHEAD + quad * 8;
    float4 k0a = *(const float4*)(kr0);      float4 k0b = *(const float4*)(kr0 + 4);
    float4 k0c = *(const float4*)(kr0 + 32); float4 k0d = *(const float4*)(kr0 + 36);
    float4 k1a = *(const float4*)(kr1);      float4 k1b = *(const float4*)(kr1 + 4);
    float4 k1c = *(const float4*)(kr1 + 32); float4 k1d = *(const float4*)(kr1 + 36);

    // V gathered in PV B-frag layout: v[tile][j][ndv] = V[4*quad+j][16*ndv+c]
    float v0[4][4], v1[4][4];
    {
        const float* vb0 = vpool + ((size_t)pb0 * BSZ * NHEAD + h) * DHEAD + c;
        const float* vb1 = vpool + ((size_t)pb1 * BSZ * NHEAD + h) * DHEAD + c;
#pragma unroll
        for (int j = 0; j < 4; ++j) {
            const float* r0 = vb0 + (size_t)(4 * quad + j) * (NHEAD * DHEAD);
            const float* r1 = vb1 + (size_t)(4 * quad + j) * (NHEAD * DHEAD);
#pragma unroll
            for (int ndv = 0; ndv < 4; ++ndv) {
                v0[j][ndv] = r0[16 * ndv];
                v1[j][ndv] = r1[16 * ndv];
            }
        }
    }
    // Pin the schedule: nothing below may be hoisted above, nothing above
    // (the loads) may sink below. Forces all loads in flight.
    __builtin_amdgcn_sched_barrier(0);
    // ======================================================================

    // ---- Q B-frags ----
    H8 qb0, qb1;
    qb0.h[0]=(_Float16)q0.x; qb0.h[1]=(_Float16)q0.y; qb0.h[2]=(_Float16)q0.z; qb0.h[3]=(_Float16)q0.w;
    qb0.h[4]=(_Float16)q1.x; qb0.h[5]=(_Float16)q1.y; qb0.h[6]=(_Float16)q1.z; qb0.h[7]=(_Float16)q1.w;
    qb1.h[0]=(_Float16)q2.x; qb1.h[1]=(_Float16)q2.y; qb1.h[2]=(_Float16)q2.z; qb1.h[3]=(_Float16)q2.w;
    qb1.h[4]=(_Float16)q3.x; qb1.h[5]=(_Float16)q3.y; qb1.h[6]=(_Float16)q3.z; qb1.h[7]=(_Float16)q3.w;

    // ---- QK MFMAs: S^T[token][query] per tile ----
    const float4v z4 = {0.f, 0.f, 0.f, 0.f};
    H8 ka, kb;
    ka.h[0]=(_Float16)k0a.x; ka.h[1]=(_Float16)k0a.y; ka.h[2]=(_Float16)k0a.z; ka.h[3]=(_Float16)k0a.w;
    ka.h[4]=(_Float16)k0b.x; ka.h[5]=(_Float16)k0b.y; ka.h[6]=(_Float16)k0b.z; ka.h[7]=(_Float16)k0b.w;
    kb.h[0]=(_Float16)k0c.x; kb.h[1]=(_Float16)k0c.y; kb.h[2]=(_Float16)k0c.z; kb.h[3]=(_Float16)k0c.w;
    kb.h[4]=(_Float16)k0d.x; kb.h[5]=(_Float16)k0d.y; kb.h[6]=(_Float16)k0d.z; kb.h[7]=(_Float16)k0d.w;
    float4v st0 = __builtin_amdgcn_mfma_f32_16x16x32_f16(ka.v, qb0.v, z4, 0, 0, 0);
    st0 = __builtin_amdgcn_mfma_f32_16x16x32_f16(kb.v, qb1.v, st0, 0, 0, 0);
    ka.h[0]=(_Float16)k1a.x; ka.h[1]=(_Float16)k1a.y; ka.h[2]=(_Float16)k1a.z; ka.h[3]=(_Float16)k1a.w;
    ka.h[4]=(_Float16)k1b.x; ka.h[5]=(_Float16)k1b.y; ka.h[6]=(_Float16)k1b.z; ka.h[7]=(_Float16)k1b.w;
    kb.h[0]=(_Float16)k1c.x; kb.h[1]=(_Float16)k1c.y; kb.h[2]=(_Float16)k1c.z; kb.h[3]=(_Float16)k1c.w;
    kb.h[4]=(_Float16)k1d.x; kb.h[5]=(_Float16)k1d.y; kb.h[6]=(_Float16)k1d.z; kb.h[7]=(_Float16)k1d.w;
    float4v st1 = __builtin_amdgcn_mfma_f32_16x16x32_f16(ka.v, qb0.v, z4, 0, 0, 0);
    st1 = __builtin_amdgcn_mfma_f32_16x16x32_f16(kb.v, qb1.v, st1, 0, 0, 0);

    // ---- causal mask (only the last block's upper tiles are affected) ----
    if (tb0 + 15 > START_POS_C) {
#pragma unroll
        for (int r = 0; r < 4; ++r)
            if (tb0 + 4 * quad + r > START_POS_C + c) st0[r] = -INFINITY;
    }
    if (tb1 + 15 > START_POS_C) {
#pragma unroll
        for (int r = 0; r < 4; ++r)
            if (tb1 + 4 * quad + r > START_POS_C + c) st1[r] = -INFINITY;
    }

    // ---- single-shot softmax over this wave's 32 tokens (per query c) ----
    float tm = fmaxf(fmaxf(fmaxf(st0[0], st0[1]), fmaxf(st0[2], st0[3])),
                     fmaxf(fmaxf(st1[0], st1[1]), fmaxf(st1[2], st1[3])));
    tm = fmaxf(tm, __shfl_xor(tm, 16, 64));
    tm = fmaxf(tm, __shfl_xor(tm, 32, 64));
    H4 pa0, pa1;
    pa0.h[0]=(_Float16)exp2f(st0[0]-tm); pa0.h[1]=(_Float16)exp2f(st0[1]-tm);
    pa0.h[2]=(_Float16)exp2f(st0[2]-tm); pa0.h[3]=(_Float16)exp2f(st0[3]-tm);
    pa1.h[0]=(_Float16)exp2f(st1[0]-tm); pa1.h[1]=(_Float16)exp2f(st1[1]-tm);
    pa1.h[2]=(_Float16)exp2f(st1[2]-tm); pa1.h[3]=(_Float16)exp2f(st1[3]-tm);
    float ts = ((float)pa0.h[0] + (float)pa0.h[1]) + ((float)pa0.h[2] + (float)pa0.h[3])
             + ((float)pa1.h[0] + (float)pa1.h[1]) + ((float)pa1.h[2] + (float)pa1.h[3]);
    ts += __shfl_xor(ts, 16, 64);
    ts += __shfl_xor(ts, 32, 64);

    // ---- PV MFMAs (no rescale — single shot) ----
    float4v acc[4];
#pragma unroll
    for (int i = 0; i < 4; ++i) acc[i] = z4;
#pragma unroll
    for (int ndv = 0; ndv < 4; ++ndv) {
        H4 bf;
        bf.h[0]=(_Float16)v0[0][ndv]; bf.h[1]=(_Float16)v0[1][ndv];
        bf.h[2]=(_Float16)v0[2][ndv]; bf.h[3]=(_Float16)v0[3][ndv];
        acc[ndv] = __builtin_amdgcn_mfma_f32_16x16x16f16(pa0.v, bf.v, acc[ndv], 0, 0, 0);
        bf.h[0]=(_Float16)v1[0][ndv]; bf.h[1]=(_Float16)v1[1][ndv];
        bf.h[2]=(_Float16)v1[2][ndv]; bf.h[3]=(_Float16)v1[3][ndv];
        acc[ndv] = __builtin_amdgcn_mfma_f32_16x16x16f16(pa1.v, bf.v, acc[ndv], 0, 0, 0);
    }

    // ---- in-block merge of 4 wave-partials ----
#pragma unroll
    for (int ndv = 0; ndv < 4; ++ndv)
#pragma unroll
        for (int r = 0; r < 4; ++r)
            sacc[w][4 * quad + r][16 * ndv + c] = acc[ndv][r];
    if (quad == 0) { sm[w][c] = tm; sse[w][c] = ts; }
    __syncthreads();

    const int q = tid >> 4;
    const int dseg = tid & 15;
    float m0 = sm[0][q], m1 = sm[1][q], m2 = sm[2][q], m3 = sm[3][q];
    float M = fmaxf(fmaxf(m0, m1), fmaxf(m2, m3));
    float u0 = exp2f(m0 - M), u1 = exp2f(m1 - M), u2 = exp2f(m2 - M), u3 = exp2f(m3 - M);
    float den = u0 * sse[0][q] + u1 * sse[1][q] + u2 * sse[2][q] + u3 * sse[3][q];
    float4v num = u0 * (*(const float4v*)&sacc[0][q][4 * dseg])
                + u1 * (*(const float4v*)&sacc[1][q][4 * dseg])
                + u2 * (*(const float4v*)&sacc[2][q][4 * dseg])
                + u3 * (*(const float4v*)&sacc[3][q][4 * dseg]);
    const size_t ob = ((size_t)(h * SPLITS + s) * L_TOK + q) * DHEAD + 4 * dseg;
    *(float4v*)&accws[ob] = num;
    if (dseg == 0) {
        const size_t mb = (size_t)(h * SPLITS + s) * L_TOK + q;
        m_arr[mb] = M;
        se_arr[mb] = den;
    }
}

// ---------------------------------------------------------------------------
// Combine split partials (unchanged).
// ---------------------------------------------------------------------------
__global__ __launch_bounds__(256) void combine(const float* __restrict__ accws,
                                               const float* __restrict__ m_arr,
                                               const float* __restrict__ se_arr,
                                               float* __restrict__ attnws) {
    const int h = blockIdx.x >> 4;
    const int l = blockIdx.x & 15;
    const int w = threadIdx.x >> 6;
    const int lane = threadIdx.x & 63;
    __shared__ float sm[4], sse[4], sacc[4][64];

    float M = -INFINITY, num = 0.f, den = 0.f;
#pragma unroll 4
    for (int s = w; s < SPLITS; s += 4) {
        const size_t idx = (size_t)(h * SPLITS + s) * L_TOK + l;
        const float ms = m_arr[idx];
        const float ses = se_arr[idx];
        const float a = accws[idx * DHEAD + lane];
        const float Mn = fmaxf(M, ms);
        const float c_old = exp2f(M - Mn);
        const float c_new = exp2f(ms - Mn);
        num = num * c_old + a * c_new;
        den = den * c_old + ses * c_new;
        M = Mn;
    }
    if (lane == 0) { sm[w] = M; sse[w] = den; }
    sacc[w][lane] = num;
    __syncthreads();
    if (w == 0) {
        const float M0 = fmaxf(fmaxf(sm[0], sm[1]), fmaxf(sm[2], sm[3]));
        float nn = 0.f, dd = 0.f;
#pragma unroll
        for (int i = 0; i < 4; ++i) {
            const float wgt = exp2f(sm[i] - M0);
            nn = fmaf(wgt, sacc[i][lane], nn);
            dd = fmaf(wgt, sse[i], dd);
        }
        attnws[(size_t)l * DMODEL + h * DHEAD + lane] = nn / dd;
    }
}

// ---------------------------------------------------------------------------
// Reduce split-K partials of final projection + bias -> d_out (unchanged).
// ---------------------------------------------------------------------------
__global__ __launch_bounds__(256) void proj_reduce(const float* __restrict__ part,
                                                   const float* __restrict__ bias,
                                                   float* __restrict__ out) {
    int tid = blockIdx.x * 256 + threadIdx.x;   // < 16384
    int n = tid & (DMODEL - 1);
    int l = tid >> 10;
    float s = bias[n];
#pragma unroll
    for (int kb = 0; kb < KSPLIT; ++kb)
        s += part[((size_t)kb * L_TOK + l) * DMODEL + n];
    out[tid] = s;
}

extern "C" void kernel_launch(void* const* d_in, const int* in_sizes, int n_in,
                              void* d_out, int out_size, void* d_ws, size_t ws_size,
                              hipStream_t stream) {
    const float* x       = (const float*)d_in[0];
    float* kpool         = (float*)d_in[1];
    float* vpool         = (float*)d_in[2];
    const float* W_attn  = (const float*)d_in[3];
    const float* b_attn  = (const float*)d_in[4];
    const float* W_proj  = (const float*)d_in[5];
    const float* b_proj  = (const float*)d_in[6];
    const int* block_ids = (const int*)d_in[7];
    float* ws  = (float*)d_ws;
    float* out = (float*)d_out;

    // 1) QKV projection (split-K partials)
    gemm_part<<<dim3(12, KSPLIT), 256, 0, stream>>>(x, W_attn, ws + OFF_QKVP, 3 * DMODEL);
    // 2) reduce + bias; q -> ws (scaled), new k/v -> pools (paged write)
    qkv_reduce_scatter<<<192, 256, 0, stream>>>(ws + OFF_QKVP, b_attn, block_ids,
                                                ws + OFF_QW, kpool, vpool);
    // 3) flash-decode attention over the full prefix (f16 MFMA, pinned loads)
    paged_attn<<<dim3(NHEAD, SPLITS), 256, 0, stream>>>(kpool, vpool, block_ids,
                                                        ws + OFF_QW, ws + OFF_ACC,
                                                        ws + OFF_M, ws + OFF_SE);
    // 4) combine splits
    combine<<<NHEAD * L_TOK, 256, 0, stream>>>(ws + OFF_ACC, ws + OFF_M, ws + OFF_SE,
                                               ws + OFF_ATTN);
    // 5) output projection (split-K partials)
    gemm_part<<<dim3(4, KSPLIT), 256, 0, stream>>>(ws + OFF_ATTN, W_proj, ws + OFF_PROJP, DMODEL);
    // 6) reduce + bias -> d_out
    proj_reduce<<<64, 256, 0, stream>>>(ws + OFF_PROJP, b_proj, out);
}